// Round 9
// baseline (74.756 us; speedup 1.0000x reference)
//
#include <hip/hip_runtime.h>
#include <math.h>

#define BB 2
#define CC 64
#define NPTS 16384
#define KK 16
#define RR 16
#define R3 4096

__device__ __forceinline__ unsigned short f2b(float f) {
  unsigned int u = __float_as_uint(f);
  unsigned int r = u + 0x7fffu + ((u >> 16) & 1u);
  return (unsigned short)(r >> 16);
}
__device__ __forceinline__ float b2f(unsigned short h) {
  return __uint_as_float(((unsigned int)h) << 16);
}

// ---------------- K1: zero scratch (all blocks) + per-(b,axis) mean (blocks 0-5)
__global__ __launch_bounds__(256) void k_zero_mean(const float* __restrict__ xyz,
                                                   float* __restrict__ meanv,
                                                   float4* __restrict__ zbase,
                                                   int zcount4) {
  int gt = blockIdx.x * 256 + threadIdx.x;
  int stride = gridDim.x * 256;
  for (int i = gt; i < zcount4; i += stride)
    zbase[i] = make_float4(0.f, 0.f, 0.f, 0.f);

  if (blockIdx.x < 6) {
    int row = blockIdx.x;  // b*3+o
    const float* src = xyz + (size_t)row * NPTS;
    float s = 0.f;
    for (int i = threadIdx.x; i < NPTS; i += 256) s += src[i];
    for (int off = 32; off; off >>= 1) s += __shfl_down(s, off, 64);
    __shared__ float ls[4];
    int lane = threadIdx.x & 63, wv = threadIdx.x >> 6;
    if (lane == 0) ls[wv] = s;
    __syncthreads();
    if (threadIdx.x == 0) meanv[row] = (ls[0] + ls[1] + ls[2] + ls[3]) / (float)NPTS;
  }
}

// ---------------- K2: fused voxelize + transpose + scatter + y1 -------------
__global__ __launch_bounds__(256) void k_prep(
    const float* __restrict__ x, const float* __restrict__ xyz,
    const float* __restrict__ meanv, const float* __restrict__ wp1,
    float* __restrict__ sumsVC, float* __restrict__ cnts,
    unsigned short* __restrict__ xTb, float* __restrict__ rec,
    float* __restrict__ ncT) {
  __shared__ float tile[64][65];
  __shared__ int lflat[64];
  int bi = blockIdx.x;  // 0..511
  int b = bi >> 8, n0 = (bi & 255) * 64;
  int t = threadIdx.x;

  // voxel part: one thread per point
  if (t < 64) {
    int n = n0 + t;
    int p = b * NPTS + n;
    float vv[3]; int vi[3];
#pragma unroll
    for (int o = 0; o < 3; ++o) {
      float v = xyz[((size_t)b * 3 + o) * NPTS + n];
      float tc = (v - meanv[b * 3 + o] + 1.0f) * 0.5f * (float)RR;
      tc = fminf(fmaxf(tc, 0.f), (float)(RR - 1));
      vv[o] = tc;
      vi[o] = (int)rintf(tc);  // round-half-even
      rec[(size_t)p * 8 + o] = v;
    }
    int f = (vi[0] * RR + vi[1]) * RR + vi[2];
    lflat[t] = f;
    atomicAdd(&cnts[b * R3 + f], 1.0f);
    ((float4*)ncT)[p] = make_float4(vv[0], vv[1], vv[2], 0.f);
  }

  int nl = t & 63, cq = t >> 6;
#pragma unroll 4
  for (int it = 0; it < 16; ++it) {
    int c = it * 4 + cq;
    tile[c][nl] = x[((size_t)b * CC + c) * NPTS + n0 + nl];
  }
  __syncthreads();
  // bf16 transpose write: lane = channel PAIR -> uint stores, 128B rows
  {
    unsigned int* xTb32 = (unsigned int*)xTb;
    int col = t & 31, rsel = t >> 5;  // rsel 0..7
#pragma unroll
    for (int it = 0; it < 8; ++it) {
      int n2 = it * 8 + rsel;
      unsigned int pk = (unsigned int)f2b(tile[2 * col][n2]) |
                        ((unsigned int)f2b(tile[2 * col + 1][n2]) << 16);
      xTb32[((size_t)(b * NPTS + n0 + n2)) * 32 + col] = pk;
    }
  }
  // voxel scatter: lane = channel, one coalesced 256B atomic row per point
  int wv = t >> 6, lane = t & 63;
#pragma unroll 2
  for (int i = 0; i < 16; ++i) {
    int n2 = wv * 16 + i;
    atomicAdd(&sumsVC[((size_t)b * R3 + lflat[n2]) * 64 + lane], tile[lane][n2]);
  }
  // y1 = wp1 * x : 192 threads, each one 64-length dot
  if (t < 192) {
    int pt = t & 63, o = t >> 6;
    const float* wr = wp1 + o * 64;
    float s = 0.f;
#pragma unroll 8
    for (int c = 0; c < 64; ++c) s += wr[c] * tile[c][pt];
    rec[((size_t)(b * NPTS + n0 + pt)) * 8 + 3 + o] = s;
  }
}

// ------- K3a: conv-a + BN + lReLU, lane = 2 channels, 8 voxels/block --------
__global__ __launch_bounds__(256) void k_conv_a(
    const float* __restrict__ sumsVC, const float* __restrict__ cnts,
    const float* __restrict__ w3a, const float* __restrict__ b3a,
    const float* __restrict__ g3a, const float* __restrict__ be3a,
    const float* __restrict__ m3a, const float* __restrict__ v3a,
    unsigned short* __restrict__ gA) {
  int bid = blockIdx.x;                 // 0..1023
  int b = (bid & 7) >> 2;               // XCD-batch swizzle
  int inner = ((bid >> 3) << 2) + (bid & 3);  // 0..511
  int t = threadIdx.x;
  int lane = t & 63, vq = t >> 6;
  int l31 = lane & 31, hw = lane >> 5;
  int c0 = 2 * l31;
  int v = inner * 8 + vq * 2 + hw;
  int d = v >> 8, h = (v >> 4) & 15, w = v & 15;
  const float2* sp2 = (const float2*)(sumsVC + (size_t)b * R3 * 64);
  const float* cp = cnts + (size_t)b * R3;
  float wk0[27], wk1[27];
#pragma unroll
  for (int i = 0; i < 27; ++i) { wk0[i] = w3a[c0 * 27 + i]; wk1[i] = w3a[(c0 + 1) * 27 + i]; }
  float a0 = 0.f, a1 = 0.f;
#pragma unroll
  for (int kd = 0; kd < 3; ++kd) {
    int dd = d + kd - 1;
    if ((unsigned)dd < 16u) {
#pragma unroll
      for (int kh = 0; kh < 3; ++kh) {
        int hh = h + kh - 1;
        if ((unsigned)hh < 16u) {
#pragma unroll
          for (int kw = 0; kw < 3; ++kw) {
            int ww = w + kw - 1;
            if ((unsigned)ww < 16u) {
              int nv = (dd << 8) + (hh << 4) + ww;
              float rc = __builtin_amdgcn_rcpf(fmaxf(cp[nv], 1.f));
              float2 sv = sp2[(size_t)nv * 32 + l31];
              int ki = kd * 9 + kh * 3 + kw;
              a0 += wk0[ki] * (sv.x * rc);
              a1 += wk1[ki] * (sv.y * rc);
            }
          }
        }
      }
    }
  }
  a0 += b3a[c0];
  a0 = (a0 - m3a[c0]) * (g3a[c0] * rsqrtf(v3a[c0] + 1e-4f)) + be3a[c0];
  a0 = a0 > 0.f ? a0 : 0.1f * a0;
  a1 += b3a[c0 + 1];
  a1 = (a1 - m3a[c0 + 1]) * (g3a[c0 + 1] * rsqrtf(v3a[c0 + 1] + 1e-4f)) + be3a[c0 + 1];
  a1 = a1 > 0.f ? a1 : 0.1f * a1;
  unsigned int* gA32 = (unsigned int*)gA;
  gA32[((size_t)b * R3 + v) * 32 + l31] =
      (unsigned int)f2b(a0) | ((unsigned int)f2b(a1) << 16);
}

// ------- K3b: conv-b + BN + lReLU, lane = 2 channels --------
__global__ __launch_bounds__(256) void k_conv_b(
    const unsigned short* __restrict__ gA,
    const float* __restrict__ w3b, const float* __restrict__ b3b,
    const float* __restrict__ g3b, const float* __restrict__ be3b,
    const float* __restrict__ m3b, const float* __restrict__ v3b,
    unsigned short* __restrict__ gridb) {
  int bid = blockIdx.x;
  int b = (bid & 7) >> 2;
  int inner = ((bid >> 3) << 2) + (bid & 3);
  int t = threadIdx.x;
  int lane = t & 63, vq = t >> 6;
  int l31 = lane & 31, hw = lane >> 5;
  int c0 = 2 * l31;
  int v = inner * 8 + vq * 2 + hw;
  int d = v >> 8, h = (v >> 4) & 15, w = v & 15;
  const unsigned int* sp32 = (const unsigned int*)(gA + (size_t)b * R3 * 64);
  float wk0[27], wk1[27];
#pragma unroll
  for (int i = 0; i < 27; ++i) { wk0[i] = w3b[c0 * 27 + i]; wk1[i] = w3b[(c0 + 1) * 27 + i]; }
  float a0 = 0.f, a1 = 0.f;
#pragma unroll
  for (int kd = 0; kd < 3; ++kd) {
    int dd = d + kd - 1;
    if ((unsigned)dd < 16u) {
#pragma unroll
      for (int kh = 0; kh < 3; ++kh) {
        int hh = h + kh - 1;
        if ((unsigned)hh < 16u) {
#pragma unroll
          for (int kw = 0; kw < 3; ++kw) {
            int ww = w + kw - 1;
            if ((unsigned)ww < 16u) {
              int nv = (dd << 8) + (hh << 4) + ww;
              unsigned int gv = sp32[(size_t)nv * 32 + l31];
              int ki = kd * 9 + kh * 3 + kw;
              a0 += wk0[ki] * b2f((unsigned short)(gv & 0xffffu));
              a1 += wk1[ki] * b2f((unsigned short)(gv >> 16));
            }
          }
        }
      }
    }
  }
  a0 += b3b[c0];
  a0 = (a0 - m3b[c0]) * (g3b[c0] * rsqrtf(v3b[c0] + 1e-4f)) + be3b[c0];
  a0 = a0 > 0.f ? a0 : 0.1f * a0;
  a1 += b3b[c0 + 1];
  a1 = (a1 - m3b[c0 + 1]) * (g3b[c0 + 1] * rsqrtf(v3b[c0 + 1] + 1e-4f)) + be3b[c0 + 1];
  a1 = a1 > 0.f ? a1 : 0.1f * a1;
  unsigned int* gb32 = (unsigned int*)gridb;
  gb32[((size_t)b * R3 + v) * 32 + l31] =
      (unsigned int)f2b(a0) | ((unsigned int)f2b(a1) << 16);
}

// ---------------- K4: trilinear + point branch + output (32 pts/block) ------
// Phase 2 channel-paired: lane = 2 channels (uint bf16x2), half-wave = point.
__global__ __launch_bounds__(256) void k_final(
    const unsigned short* __restrict__ xTb, const float* __restrict__ rec,
    const float* __restrict__ ncT, const unsigned short* __restrict__ gridb,
    const int* __restrict__ idx,
    const float* __restrict__ gp, const float* __restrict__ bp,
    const float* __restrict__ mp, const float* __restrict__ vp,
    const float* __restrict__ wp2,
    const float* __restrict__ gt, const float* __restrict__ bt,
    const float* __restrict__ mt, const float* __restrict__ vt,
    float* __restrict__ out) {
  __shared__ float wgt[32 * 16 * 7];  // [pl][k][7]: 0-5 weights, 6 = j bits
  __shared__ float rloc[32 * 8];      // center-point records
  __shared__ float res[64][33];
  int t = threadIdx.x;
  int g = blockIdx.x;                 // 0..1023
  // XCD-batch swizzle: XCDs 0-3 -> batch 0, XCDs 4-7 -> batch 1.
  int b = (g & 7) >> 2;
  int w = ((g >> 3) << 2) + (g & 3);  // 0..511 within batch
  int n0 = w * 32;
  int p0 = b * NPTS + n0;
  int bBase = b * NPTS;
  const float4* rec4 = (const float4*)rec;

  // ---- phase 0: stage the 32 center records in LDS (64 coalesced float4) ---
  if (t < 64) ((float4*)rloc)[t] = rec4[(size_t)p0 * 2 + t];
  __syncthreads();

  // ---- phase 1: 512 (point,k) pairs ----
  {
    float sp0 = gp[0] * rsqrtf(vp[0] + 1e-5f);
    float sp1 = gp[1] * rsqrtf(vp[1] + 1e-5f);
    float sp2 = gp[2] * rsqrtf(vp[2] + 1e-5f);
    float mp0 = mp[0], mp1 = mp[1], mp2 = mp[2];
    float bp0 = bp[0], bp1 = bp[1], bp2 = bp[2];
#pragma unroll
    for (int it = 0; it < 2; ++it) {
      int pair = t + it * 256;         // 0..511
      int pl = pair >> 4, k = pair & 15;
      int p = p0 + pl;
      int j = idx[(size_t)p * 16 + k];
      float4 r0 = ((const float4*)rloc)[pl * 2];
      float4 r1 = ((const float4*)rloc)[pl * 2 + 1];
      int pj = bBase + j;
      float4 q0 = rec4[(size_t)pj * 2], q1 = rec4[(size_t)pj * 2 + 1];
      float d0 = q0.x - r0.x, d1 = q0.y - r0.y, d2 = q0.z - r0.z;
      float e0 = q0.w - r0.w, e1 = q1.x - r1.x, e2 = q1.y - r1.y;
      float t0 = fmaxf((e0 - mp0) * sp0 + bp0, 0.f);
      float t1 = fmaxf((e1 - mp1) * sp1 + bp1, 0.f);
      float t2 = fmaxf((e2 - mp2) * sp2 + bp2, 0.f);
      float* wp = &wgt[pair * 7];
      wp[0] = d0; wp[1] = d1; wp[2] = d2;
      wp[3] = wp2[0] * t0 + wp2[1] * t1 + wp2[2] * t2;
      wp[4] = wp2[3] * t0 + wp2[4] * t1 + wp2[5] * t2;
      wp[5] = wp2[6] * t0 + wp2[7] * t1 + wp2[8] * t2;
      ((int*)wp)[6] = j;
    }
  }
  __syncthreads();

  // ---- phase 2: channel-paired gathers ----
  int lane = t & 63, wv = t >> 6;
  int hw = lane >> 5;            // which point of the pair
  int l31 = lane & 31;
  int c0 = l31 * 2;              // channels c0, c0+1
  float st0 = gt[c0] * rsqrtf(vt[c0] + 1e-5f);
  float st1 = gt[c0 + 1] * rsqrtf(vt[c0 + 1] + 1e-5f);
  float mt0 = mt[c0], mt1 = mt[c0 + 1];
  float bt0 = bt[c0], bt1 = bt[c0 + 1];
  int part0 = c0 / 10; if (part0 > 5) part0 = 5;
  int part1 = (c0 + 1) / 10; if (part1 > 5) part1 = 5;
  const float4* nc4 = (const float4*)ncT;
  const unsigned int* gbase32 = (const unsigned int*)(gridb + (size_t)b * R3 * 64);
  const unsigned int* xTb32 = (const unsigned int*)xTb;

#pragma unroll
  for (int pi = 0; pi < 4; ++pi) {
    int pl = wv * 8 + pi * 2 + hw;
    int p = p0 + pl;
    // trilinear: each gather = 32 lanes x 4B x 2 half-waves = 256B
    float4 ncv = nc4[p];
    float c0x = floorf(ncv.x), c0y = floorf(ncv.y), c0z = floorf(ncv.z);
    int i0x = (int)c0x, i0y = (int)c0y, i0z = (int)c0z;
    int i1x = min(i0x + 1, 15), i1y = min(i0y + 1, 15), i1z = min(i0z + 1, 15);
    float fx = ncv.x - c0x, fy = ncv.y - c0y, fz = ncv.z - c0z;
    float pv0 = 0.f, pv1 = 0.f;
#pragma unroll
    for (int dx = 0; dx < 2; ++dx)
#pragma unroll
      for (int dy = 0; dy < 2; ++dy)
#pragma unroll
        for (int dz = 0; dz < 2; ++dz) {
          int ix = dx ? i1x : i0x, iy = dy ? i1y : i0y, iz = dz ? i1z : i0z;
          float wg = (dx ? fx : 1.f - fx) * (dy ? fy : 1.f - fy) * (dz ? fz : 1.f - fz);
          unsigned int gv = gbase32[(size_t)((ix * 16 + iy) * 16 + iz) * 32 + l31];
          pv0 += wg * b2f((unsigned short)(gv & 0xffffu));
          pv1 += wg * b2f((unsigned short)(gv >> 16));
        }
    // point branch: 16 neighbor gathers, 2 channels per lane
    const float* wrow = &wgt[pl * 16 * 7];
    int jv[16];
#pragma unroll
    for (int k = 0; k < 16; ++k) jv[k] = ((const int*)wrow)[k * 7 + 6];
    unsigned int xv[16];
#pragma unroll
    for (int k = 0; k < 16; ++k)
      xv[k] = xTb32[(size_t)(bBase + jv[k]) * 32 + l31];
    float a0 = -1e30f, a1 = -1e30f;
#pragma unroll
    for (int k = 0; k < 16; ++k) {
      float w20 = wrow[k * 7 + part0];
      float w21 = wrow[k * 7 + part1];
      float x0 = b2f((unsigned short)(xv[k] & 0xffffu));
      float x1 = b2f((unsigned short)(xv[k] >> 16));
      a0 = fmaxf(a0, fmaxf((x0 * w20 - mt0) * st0 + bt0, 0.f));
      a1 = fmaxf(a1, fmaxf((x1 * w21 - mt1) * st1 + bt1, 0.f));
    }
    res[c0][pl] = pv0 + a0;
    res[c0 + 1][pl] = pv1 + a1;
  }
  __syncthreads();
  int col = t & 31, rq = t >> 5;  // rq 0..7
#pragma unroll
  for (int r = 0; r < 8; ++r) {
    int row = rq + r * 8;  // channel 0..63
    out[((size_t)(b * CC + row)) * NPTS + n0 + col] = res[row][col];
  }
}

extern "C" void kernel_launch(void* const* d_in, const int* in_sizes, int n_in,
                              void* d_out, int out_size, void* d_ws, size_t ws_size,
                              hipStream_t stream) {
  const float* x    = (const float*)d_in[0];
  const float* xyz  = (const float*)d_in[1];
  const int*   idx  = (const int*)d_in[2];
  const float* w3a  = (const float*)d_in[3];
  const float* b3a  = (const float*)d_in[4];
  const float* g3a  = (const float*)d_in[5];
  const float* be3a = (const float*)d_in[6];
  const float* m3a  = (const float*)d_in[7];
  const float* v3a  = (const float*)d_in[8];
  const float* w3b  = (const float*)d_in[9];
  const float* b3b  = (const float*)d_in[10];
  const float* g3b  = (const float*)d_in[11];
  const float* be3b = (const float*)d_in[12];
  const float* m3b  = (const float*)d_in[13];
  const float* v3b  = (const float*)d_in[14];
  const float* wp1  = (const float*)d_in[15];
  const float* gp   = (const float*)d_in[16];
  const float* bp   = (const float*)d_in[17];
  const float* mp   = (const float*)d_in[18];
  const float* vp   = (const float*)d_in[19];
  const float* wp2  = (const float*)d_in[20];
  const float* gt   = (const float*)d_in[21];
  const float* bt   = (const float*)d_in[22];
  const float* mt   = (const float*)d_in[23];
  const float* vt   = (const float*)d_in[24];

  float* ws     = (float*)d_ws;
  float* sumsVC = ws;                          // B*4096*64 = 524288 f32
  float* cnts   = sumsVC + 524288;             // B*4096    =   8192
  float* meanv  = cnts + 8192;                 //                  8
  float* ncT    = meanv + 8;                   // B*N*4     = 131072
  float* rec    = ncT + 131072;                // B*N*8     = 262144
  unsigned short* xTb   = (unsigned short*)(rec + 262144);  // B*N*64 bf16
  unsigned short* gridb = xTb + 2097152;                    // B*4096*64 bf16
  unsigned short* gA    = gridb + 524288;                   // B*4096*64 bf16

  k_zero_mean<<<256, 256, 0, stream>>>(xyz, meanv, (float4*)sumsVC, 133120);
  k_prep<<<512, 256, 0, stream>>>(x, xyz, meanv, wp1, sumsVC, cnts, xTb, rec, ncT);
  k_conv_a<<<1024, 256, 0, stream>>>(sumsVC, cnts, w3a, b3a, g3a, be3a, m3a, v3a, gA);
  k_conv_b<<<1024, 256, 0, stream>>>(gA, w3b, b3b, g3b, be3b, m3b, v3b, gridb);
  k_final<<<1024, 256, 0, stream>>>(xTb, rec, ncT, gridb, idx,
                                    gp, bp, mp, vp, wp2,
                                    gt, bt, mt, vt, (float*)d_out);
}

// Round 10
// 71.319 us; speedup vs baseline: 1.0482x; 1.0482x over previous
//
#include <hip/hip_runtime.h>
#include <math.h>

#define BB 2
#define CC 64
#define NPTS 16384
#define KK 16
#define RR 16
#define R3 4096

__device__ __forceinline__ unsigned short f2b(float f) {
  unsigned int u = __float_as_uint(f);
  unsigned int r = u + 0x7fffu + ((u >> 16) & 1u);
  return (unsigned short)(r >> 16);
}
__device__ __forceinline__ float b2f(unsigned short h) {
  return __uint_as_float(((unsigned int)h) << 16);
}

// ---------------- K1: zero scratch (all blocks) + per-(b,axis) mean (blocks 0-5)
__global__ __launch_bounds__(256) void k_zero_mean(const float* __restrict__ xyz,
                                                   float* __restrict__ meanv,
                                                   float4* __restrict__ zbase,
                                                   int zcount4) {
  int gt = blockIdx.x * 256 + threadIdx.x;
  int stride = gridDim.x * 256;
  for (int i = gt; i < zcount4; i += stride)
    zbase[i] = make_float4(0.f, 0.f, 0.f, 0.f);

  if (blockIdx.x < 6) {
    int row = blockIdx.x;  // b*3+o
    const float* src = xyz + (size_t)row * NPTS;
    float s = 0.f;
    for (int i = threadIdx.x; i < NPTS; i += 256) s += src[i];
    for (int off = 32; off; off >>= 1) s += __shfl_down(s, off, 64);
    __shared__ float ls[4];
    int lane = threadIdx.x & 63, wv = threadIdx.x >> 6;
    if (lane == 0) ls[wv] = s;
    __syncthreads();
    if (threadIdx.x == 0) meanv[row] = (ls[0] + ls[1] + ls[2] + ls[3]) / (float)NPTS;
  }
}

// ---------------- K2: fused voxelize + transpose + scatter + y1 -------------
__global__ __launch_bounds__(256) void k_prep(
    const float* __restrict__ x, const float* __restrict__ xyz,
    const float* __restrict__ meanv, const float* __restrict__ wp1,
    float* __restrict__ sumsVC, float* __restrict__ cnts,
    unsigned short* __restrict__ xTb, float* __restrict__ rec,
    float* __restrict__ ncT) {
  __shared__ float tile[64][65];
  __shared__ int lflat[64];
  int bi = blockIdx.x;  // 0..511
  int b = bi >> 8, n0 = (bi & 255) * 64;
  int t = threadIdx.x;

  // voxel part: one thread per point
  if (t < 64) {
    int n = n0 + t;
    int p = b * NPTS + n;
    float vv[3]; int vi[3];
#pragma unroll
    for (int o = 0; o < 3; ++o) {
      float v = xyz[((size_t)b * 3 + o) * NPTS + n];
      float tc = (v - meanv[b * 3 + o] + 1.0f) * 0.5f * (float)RR;
      tc = fminf(fmaxf(tc, 0.f), (float)(RR - 1));
      vv[o] = tc;
      vi[o] = (int)rintf(tc);  // round-half-even
      rec[(size_t)p * 8 + o] = v;
    }
    int f = (vi[0] * RR + vi[1]) * RR + vi[2];
    lflat[t] = f;
    atomicAdd(&cnts[b * R3 + f], 1.0f);
    ((float4*)ncT)[p] = make_float4(vv[0], vv[1], vv[2], 0.f);
  }

  int nl = t & 63, cq = t >> 6;
#pragma unroll 4
  for (int it = 0; it < 16; ++it) {
    int c = it * 4 + cq;
    tile[c][nl] = x[((size_t)b * CC + c) * NPTS + n0 + nl];
  }
  __syncthreads();
  // bf16 transpose write: lanes = channels -> 128B coalesced rows
  int cw = t & 63, nq = t >> 6;
#pragma unroll 4
  for (int it = 0; it < 16; ++it) {
    int n2 = it * 4 + nq;
    xTb[((size_t)(b * NPTS + n0 + n2)) * 64 + cw] = f2b(tile[cw][n2]);
  }
  // voxel scatter: lane = channel, one coalesced 256B atomic row per point
  int wv = t >> 6, lane = t & 63;
#pragma unroll 2
  for (int i = 0; i < 16; ++i) {
    int n2 = wv * 16 + i;
    atomicAdd(&sumsVC[((size_t)b * R3 + lflat[n2]) * 64 + lane], tile[lane][n2]);
  }
  // y1 = wp1 * x : 192 threads, each one 64-length dot
  if (t < 192) {
    int pt = t & 63, o = t >> 6;
    const float* wr = wp1 + o * 64;
    float s = 0.f;
#pragma unroll 8
    for (int c = 0; c < 64; ++c) s += wr[c] * tile[c][pt];
    rec[((size_t)(b * NPTS + n0 + pt)) * 8 + 3 + o] = s;
  }
}

// ---------------- K3a: depthwise conv-a + BN + lReLU (1 thread per (v,c)) ---
__global__ __launch_bounds__(256) void k_conv_a(
    const float* __restrict__ sumsVC, const float* __restrict__ cnts,
    const float* __restrict__ w3a, const float* __restrict__ b3a,
    const float* __restrict__ g3a, const float* __restrict__ be3a,
    const float* __restrict__ m3a, const float* __restrict__ v3a,
    unsigned short* __restrict__ gA) {
  int bid = blockIdx.x;                 // 0..2047
  int b = (bid & 7) >> 2;               // XCD-batch swizzle
  int inner = ((bid >> 3) << 2) + (bid & 3);  // 0..1023
  int t = threadIdx.x;
  int c = t & 63, vq = t >> 6;
  int v = inner * 4 + vq;               // wave-uniform voxel
  int d = v >> 8, h = (v >> 4) & 15, w = v & 15;
  const float* sp = sumsVC + (size_t)b * R3 * 64;
  const float* cp = cnts + (size_t)b * R3;
  float wk[27];
#pragma unroll
  for (int i = 0; i < 27; ++i) wk[i] = w3a[c * 27 + i];
  float acc = 0.f;
#pragma unroll
  for (int kd = 0; kd < 3; ++kd) {
    int dd = d + kd - 1;
    if ((unsigned)dd < 16u) {
#pragma unroll
      for (int kh = 0; kh < 3; ++kh) {
        int hh = h + kh - 1;
        if ((unsigned)hh < 16u) {
#pragma unroll
          for (int kw = 0; kw < 3; ++kw) {
            int ww = w + kw - 1;
            if ((unsigned)ww < 16u) {
              int nv = (dd << 8) + (hh << 4) + ww;
              float rc = __builtin_amdgcn_rcpf(fmaxf(cp[nv], 1.f));
              acc += wk[kd * 9 + kh * 3 + kw] * (sp[(size_t)nv * 64 + c] * rc);
            }
          }
        }
      }
    }
  }
  acc += b3a[c];
  acc = (acc - m3a[c]) * (g3a[c] * rsqrtf(v3a[c] + 1e-4f)) + be3a[c];
  acc = acc > 0.f ? acc : 0.1f * acc;
  gA[((size_t)b * R3 + v) * 64 + c] = f2b(acc);
}

// ---------------- K3b: depthwise conv-b + BN + lReLU --------------------
__global__ __launch_bounds__(256) void k_conv_b(
    const unsigned short* __restrict__ gA,
    const float* __restrict__ w3b, const float* __restrict__ b3b,
    const float* __restrict__ g3b, const float* __restrict__ be3b,
    const float* __restrict__ m3b, const float* __restrict__ v3b,
    unsigned short* __restrict__ gridb) {
  int bid = blockIdx.x;
  int b = (bid & 7) >> 2;
  int inner = ((bid >> 3) << 2) + (bid & 3);
  int t = threadIdx.x;
  int c = t & 63, vq = t >> 6;
  int v = inner * 4 + vq;
  int d = v >> 8, h = (v >> 4) & 15, w = v & 15;
  const unsigned short* sp = gA + (size_t)b * R3 * 64;
  float wk[27];
#pragma unroll
  for (int i = 0; i < 27; ++i) wk[i] = w3b[c * 27 + i];
  float acc = 0.f;
#pragma unroll
  for (int kd = 0; kd < 3; ++kd) {
    int dd = d + kd - 1;
    if ((unsigned)dd < 16u) {
#pragma unroll
      for (int kh = 0; kh < 3; ++kh) {
        int hh = h + kh - 1;
        if ((unsigned)hh < 16u) {
#pragma unroll
          for (int kw = 0; kw < 3; ++kw) {
            int ww = w + kw - 1;
            if ((unsigned)ww < 16u) {
              int nv = (dd << 8) + (hh << 4) + ww;
              acc += wk[kd * 9 + kh * 3 + kw] * b2f(sp[(size_t)nv * 64 + c]);
            }
          }
        }
      }
    }
  }
  acc += b3b[c];
  acc = (acc - m3b[c]) * (g3b[c] * rsqrtf(v3b[c] + 1e-4f)) + be3b[c];
  acc = acc > 0.f ? acc : 0.1f * acc;
  gridb[((size_t)b * R3 + v) * 64 + c] = f2b(acc);
}

// ---------------- K4: trilinear + point branch + output (32 pts/block) ------
// Phase 2 channel-paired: lane = 2 channels (uint bf16x2), half-wave = point.
__global__ __launch_bounds__(256) void k_final(
    const unsigned short* __restrict__ xTb, const float* __restrict__ rec,
    const float* __restrict__ ncT, const unsigned short* __restrict__ gridb,
    const int* __restrict__ idx,
    const float* __restrict__ gp, const float* __restrict__ bp,
    const float* __restrict__ mp, const float* __restrict__ vp,
    const float* __restrict__ wp2,
    const float* __restrict__ gt, const float* __restrict__ bt,
    const float* __restrict__ mt, const float* __restrict__ vt,
    float* __restrict__ out) {
  __shared__ float wgt[32 * 16 * 7];  // [pl][k][7]: 0-5 = weights, 6 = j bits
  __shared__ float res[64][33];
  int t = threadIdx.x;
  int g = blockIdx.x;                 // 0..1023
  // XCD-batch swizzle: XCDs 0-3 -> batch 0, XCDs 4-7 -> batch 1.
  int b = (g & 7) >> 2;
  int w = ((g >> 3) << 2) + (g & 3);  // 0..511 within batch
  int n0 = w * 32;
  int p0 = b * NPTS + n0;
  int bBase = b * NPTS;
  const float4* rec4 = (const float4*)rec;

  // ---- phase 1: 512 (point,k) pairs ----
  {
    float sp0 = gp[0] * rsqrtf(vp[0] + 1e-5f);
    float sp1 = gp[1] * rsqrtf(vp[1] + 1e-5f);
    float sp2 = gp[2] * rsqrtf(vp[2] + 1e-5f);
    float mp0 = mp[0], mp1 = mp[1], mp2 = mp[2];
    float bp0 = bp[0], bp1 = bp[1], bp2 = bp[2];
#pragma unroll
    for (int it = 0; it < 2; ++it) {
      int pair = t + it * 256;         // 0..511
      int pl = pair >> 4, k = pair & 15;
      int p = p0 + pl;
      int j = idx[(size_t)p * 16 + k];
      float4 r0 = rec4[(size_t)p * 2], r1 = rec4[(size_t)p * 2 + 1];
      int pj = bBase + j;
      float4 q0 = rec4[(size_t)pj * 2], q1 = rec4[(size_t)pj * 2 + 1];
      float d0 = q0.x - r0.x, d1 = q0.y - r0.y, d2 = q0.z - r0.z;
      float e0 = q0.w - r0.w, e1 = q1.x - r1.x, e2 = q1.y - r1.y;
      float t0 = fmaxf((e0 - mp0) * sp0 + bp0, 0.f);
      float t1 = fmaxf((e1 - mp1) * sp1 + bp1, 0.f);
      float t2 = fmaxf((e2 - mp2) * sp2 + bp2, 0.f);
      float* wp = &wgt[pair * 7];
      wp[0] = d0; wp[1] = d1; wp[2] = d2;
      wp[3] = wp2[0] * t0 + wp2[1] * t1 + wp2[2] * t2;
      wp[4] = wp2[3] * t0 + wp2[4] * t1 + wp2[5] * t2;
      wp[5] = wp2[6] * t0 + wp2[7] * t1 + wp2[8] * t2;
      ((int*)wp)[6] = j;
    }
  }
  __syncthreads();

  // ---- phase 2: channel-paired gathers ----
  int lane = t & 63, wv = t >> 6;
  int hw = lane >> 5;            // which point of the pair
  int l31 = lane & 31;
  int c0 = l31 * 2;              // channels c0, c0+1
  float st0 = gt[c0] * rsqrtf(vt[c0] + 1e-5f);
  float st1 = gt[c0 + 1] * rsqrtf(vt[c0 + 1] + 1e-5f);
  float mt0 = mt[c0], mt1 = mt[c0 + 1];
  float bt0 = bt[c0], bt1 = bt[c0 + 1];
  int part0 = c0 / 10; if (part0 > 5) part0 = 5;
  int part1 = (c0 + 1) / 10; if (part1 > 5) part1 = 5;
  const float4* nc4 = (const float4*)ncT;
  const unsigned int* gbase32 = (const unsigned int*)(gridb + (size_t)b * R3 * 64);
  const unsigned int* xTb32 = (const unsigned int*)xTb;

#pragma unroll
  for (int pi = 0; pi < 4; ++pi) {
    int pl = wv * 8 + pi * 2 + hw;
    int p = p0 + pl;
    // trilinear: each gather = 32 lanes x 4B x 2 half-waves = 256B
    float4 ncv = nc4[p];
    float c0x = floorf(ncv.x), c0y = floorf(ncv.y), c0z = floorf(ncv.z);
    int i0x = (int)c0x, i0y = (int)c0y, i0z = (int)c0z;
    int i1x = min(i0x + 1, 15), i1y = min(i0y + 1, 15), i1z = min(i0z + 1, 15);
    float fx = ncv.x - c0x, fy = ncv.y - c0y, fz = ncv.z - c0z;
    float pv0 = 0.f, pv1 = 0.f;
#pragma unroll
    for (int dx = 0; dx < 2; ++dx)
#pragma unroll
      for (int dy = 0; dy < 2; ++dy)
#pragma unroll
        for (int dz = 0; dz < 2; ++dz) {
          int ix = dx ? i1x : i0x, iy = dy ? i1y : i0y, iz = dz ? i1z : i0z;
          float wg = (dx ? fx : 1.f - fx) * (dy ? fy : 1.f - fy) * (dz ? fz : 1.f - fz);
          unsigned int gv = gbase32[(size_t)((ix * 16 + iy) * 16 + iz) * 32 + l31];
          pv0 += wg * b2f((unsigned short)(gv & 0xffffu));
          pv1 += wg * b2f((unsigned short)(gv >> 16));
        }
    // point branch: 16 neighbor gathers, 2 channels per lane
    const float* wrow = &wgt[pl * 16 * 7];
    int jv[16];
#pragma unroll
    for (int k = 0; k < 16; ++k) jv[k] = ((const int*)wrow)[k * 7 + 6];
    unsigned int xv[16];
#pragma unroll
    for (int k = 0; k < 16; ++k)
      xv[k] = xTb32[(size_t)(bBase + jv[k]) * 32 + l31];
    float a0 = -1e30f, a1 = -1e30f;
#pragma unroll
    for (int k = 0; k < 16; ++k) {
      float w20 = wrow[k * 7 + part0];
      float w21 = wrow[k * 7 + part1];
      float x0 = b2f((unsigned short)(xv[k] & 0xffffu));
      float x1 = b2f((unsigned short)(xv[k] >> 16));
      a0 = fmaxf(a0, fmaxf((x0 * w20 - mt0) * st0 + bt0, 0.f));
      a1 = fmaxf(a1, fmaxf((x1 * w21 - mt1) * st1 + bt1, 0.f));
    }
    res[c0][pl] = pv0 + a0;
    res[c0 + 1][pl] = pv1 + a1;
  }
  __syncthreads();
  int col = t & 31, rq = t >> 5;  // rq 0..7
#pragma unroll
  for (int r = 0; r < 8; ++r) {
    int row = rq + r * 8;  // channel 0..63
    out[((size_t)(b * CC + row)) * NPTS + n0 + col] = res[row][col];
  }
}

extern "C" void kernel_launch(void* const* d_in, const int* in_sizes, int n_in,
                              void* d_out, int out_size, void* d_ws, size_t ws_size,
                              hipStream_t stream) {
  const float* x    = (const float*)d_in[0];
  const float* xyz  = (const float*)d_in[1];
  const int*   idx  = (const int*)d_in[2];
  const float* w3a  = (const float*)d_in[3];
  const float* b3a  = (const float*)d_in[4];
  const float* g3a  = (const float*)d_in[5];
  const float* be3a = (const float*)d_in[6];
  const float* m3a  = (const float*)d_in[7];
  const float* v3a  = (const float*)d_in[8];
  const float* w3b  = (const float*)d_in[9];
  const float* b3b  = (const float*)d_in[10];
  const float* g3b  = (const float*)d_in[11];
  const float* be3b = (const float*)d_in[12];
  const float* m3b  = (const float*)d_in[13];
  const float* v3b  = (const float*)d_in[14];
  const float* wp1  = (const float*)d_in[15];
  const float* gp   = (const float*)d_in[16];
  const float* bp   = (const float*)d_in[17];
  const float* mp   = (const float*)d_in[18];
  const float* vp   = (const float*)d_in[19];
  const float* wp2  = (const float*)d_in[20];
  const float* gt   = (const float*)d_in[21];
  const float* bt   = (const float*)d_in[22];
  const float* mt   = (const float*)d_in[23];
  const float* vt   = (const float*)d_in[24];

  float* ws     = (float*)d_ws;
  float* sumsVC = ws;                          // B*4096*64 = 524288 f32
  float* cnts   = sumsVC + 524288;             // B*4096    =   8192
  float* meanv  = cnts + 8192;                 //                  8
  float* ncT    = meanv + 8;                   // B*N*4     = 131072
  float* rec    = ncT + 131072;                // B*N*8     = 262144
  unsigned short* xTb   = (unsigned short*)(rec + 262144);  // B*N*64 bf16
  unsigned short* gridb = xTb + 2097152;                    // B*4096*64 bf16
  unsigned short* gA    = gridb + 524288;                   // B*4096*64 bf16

  k_zero_mean<<<256, 256, 0, stream>>>(xyz, meanv, (float4*)sumsVC, 133120);
  k_prep<<<512, 256, 0, stream>>>(x, xyz, meanv, wp1, sumsVC, cnts, xTb, rec, ncT);
  k_conv_a<<<2048, 256, 0, stream>>>(sumsVC, cnts, w3a, b3a, g3a, be3a, m3a, v3a, gA);
  k_conv_b<<<2048, 256, 0, stream>>>(gA, w3b, b3b, g3b, be3b, m3b, v3b, gridb);
  k_final<<<1024, 256, 0, stream>>>(xTb, rec, ncT, gridb, idx,
                                    gp, bp, mp, vp, wp2,
                                    gt, bt, mt, vt, (float*)d_out);
}